// Round 1
// baseline (214.279 us; speedup 1.0000x reference)
//
#include <hip/hip_runtime.h>
#include <hip/hip_bf16.h>

using bf16 = __hip_bfloat16;
typedef __attribute__((ext_vector_type(8))) short  bfrag;  // 8 bf16 (4 VGPRs)
typedef __attribute__((ext_vector_type(4))) float  ffrag;  // 4 f32 acc

#define DEVFN static __device__ __forceinline__

constexpr int BATCH  = 64;
constexpr int NPG    = 1024;
constexpr int IN_DIM = 64;
constexpr int HID    = 256;
constexpr int EMB    = 128;
constexpr int NPAIR  = BATCH * NPG / 2;   // 32768 unique rows
constexpr float TAU    = 0.25f;
constexpr float LN_EPS = 1e-5f;

DEVFN float b2f(unsigned short u) {
    union { unsigned int i; float f; } x; x.i = ((unsigned int)u) << 16; return x.f;
}
DEVFN unsigned short f2b(float f) {
    bf16 h = __float2bfloat16(f);
    unsigned short u; __builtin_memcpy(&u, &h, 2); return u;
}

// ---------------------------------------------------------------------------
// Transpose + cast weights to bf16 (N x K layout so the MFMA B-operand loads
// with the same contiguous-k ds_read_b128 pattern as the A-operand).
__global__ __launch_bounds__(256) void prep_w_kernel(
    const float* __restrict__ Win, const float* __restrict__ Wb,
    const float* __restrict__ Wout,
    unsigned short* __restrict__ WinT, unsigned short* __restrict__ WbT,
    unsigned short* __restrict__ WoutT)
{
    int idx = blockIdx.x * 256 + threadIdx.x;          // 0 .. 196607 == 3*256*256
    {   // WbT[blk][n][k] = Wb[blk][k][n]
        int blk = idx >> 16, r = idx & 65535;
        int n = r >> 8, k = r & 255;
        WbT[idx] = f2b(Wb[blk * 65536 + k * 256 + n]);
    }
    if (idx < HID * IN_DIM) {                          // WinT[n][k] = Win[k][n]
        int n = idx >> 6, k = idx & 63;
        WinT[idx] = f2b(Win[k * HID + n]);
    }
    if (idx < EMB * HID) {                             // WoutT[n][k] = Wout[k][n]
        int n = idx >> 8, k = idx & 255;
        WoutT[idx] = f2b(Wout[k * EMB + n]);
    }
}

// X[p][c] = |H[li_p][c] - H[ri_p][c]|  (bf16), one row per pair
__global__ __launch_bounds__(256) void build_x_kernel(
    const float* __restrict__ H, const int* __restrict__ pairs,
    unsigned short* __restrict__ X)
{
    int idx = blockIdx.x * 256 + threadIdx.x;          // NPAIR*64 total
    int p = idx >> 6, c = idx & 63;
    int li = pairs[2 * p], ri = pairs[2 * p + 1];
    float d = fabsf(H[(size_t)li * IN_DIM + c] - H[(size_t)ri * IN_DIM + c]);
    X[idx] = f2b(d);
}

// ---------------------------------------------------------------------------
// GEMM  Out(MxN) = A(MxK) @ Bt^T  with fused epilogue.
// MODE 0: +bias                         (input projection)
// MODE 1: h_new = A + relu(LN(.)g+b)    (residual block, K==N==256)
// MODE 2: z = LN(.)g+b, also sqout=||z||^2  (final LN)
// BM=64, full N per workgroup (so LN rows never cross workgroups).
template<int K, int N, int MODE>
__global__ __launch_bounds__(256) void gemm_epi_kernel(
    const unsigned short* __restrict__ A,
    const unsigned short* __restrict__ Bt,     // N x K
    const float* __restrict__ bias,
    const float* __restrict__ gamma,
    const float* __restrict__ beta,
    unsigned short* __restrict__ Out,
    float* __restrict__ sqout)
{
    constexpr int BM = 64, BK = 32, LDA_ = BK + 8;   // pad -> 80B row stride
    constexpr int WN = N / 64;        // waves across N (4 for 256, 2 for 128)
    constexpr int WM = 4 / WN;        // waves across M
    constexpr int RM = (BM / WM) / 16;
    constexpr int RN = 4;

    __shared__ __align__(16) short As[BM * LDA_];
    __shared__ __align__(16) short Bs[N * LDA_];
    __shared__ float part[BM][8];

    const int tid  = threadIdx.x;
    const int wave = tid >> 6, lane = tid & 63;
    const int quad = lane >> 4, l16 = lane & 15;
    const int wrow = (wave / WN) * (BM / WM);
    const int wcol = (wave % WN) * 64;
    const int m0 = blockIdx.x * BM;

    ffrag acc[RM][RN];
    #pragma unroll
    for (int i = 0; i < RM; i++)
        #pragma unroll
        for (int j = 0; j < RN; j++)
            #pragma unroll
            for (int r = 0; r < 4; r++) acc[i][j][r] = 0.f;

    for (int k0 = 0; k0 < K; k0 += BK) {
        __syncthreads();
        {   // stage A tile 64x32 (8 bf16 / thread, coalesced 16B)
            int r = tid >> 2, c = (tid & 3) * 8;
            *(bfrag*)&As[r * LDA_ + c] =
                *(const bfrag*)(A + (size_t)(m0 + r) * K + k0 + c);
        }
        #pragma unroll
        for (int it = 0; it < N / 64; ++it) {   // stage Bt tile Nx32
            int idx = tid + it * 256;
            int r = idx >> 2, c = (idx & 3) * 8;
            *(bfrag*)&Bs[r * LDA_ + c] =
                *(const bfrag*)(Bt + (size_t)r * K + k0 + c);
        }
        __syncthreads();
        bfrag af[RM], bfv[RN];
        #pragma unroll
        for (int i = 0; i < RM; i++)
            af[i] = *(const bfrag*)&As[(wrow + i * 16 + l16) * LDA_ + quad * 8];
        #pragma unroll
        for (int j = 0; j < RN; j++)
            bfv[j] = *(const bfrag*)&Bs[(wcol + j * 16 + l16) * LDA_ + quad * 8];
        #pragma unroll
        for (int i = 0; i < RM; i++)
            #pragma unroll
            for (int j = 0; j < RN; j++)
                acc[i][j] = __builtin_amdgcn_mfma_f32_16x16x32_bf16(
                                af[i], bfv[j], acc[i][j], 0, 0, 0);
    }

    float bia[RN], gam[RN], bet[RN];
    #pragma unroll
    for (int j = 0; j < RN; j++) {
        int gcol = wcol + j * 16 + l16;
        bia[j] = bias[gcol];
        if constexpr (MODE != 0) { gam[j] = gamma[gcol]; bet[j] = beta[gcol]; }
    }
    #pragma unroll
    for (int i = 0; i < RM; i++)
        #pragma unroll
        for (int j = 0; j < RN; j++)
            #pragma unroll
            for (int r = 0; r < 4; r++) acc[i][j][r] += bia[j];

    if constexpr (MODE == 0) {
        #pragma unroll
        for (int i = 0; i < RM; i++)
            #pragma unroll
            for (int j = 0; j < RN; j++) {
                int gcol = wcol + j * 16 + l16;
                #pragma unroll
                for (int r = 0; r < 4; r++) {
                    int grow = m0 + wrow + i * 16 + quad * 4 + r;
                    Out[(size_t)grow * N + gcol] = f2b(acc[i][j][r]);
                }
            }
    } else {
        // per-row LN stats: lane partials over j, xor-shuffle over l16,
        // cross-wave via LDS
        #pragma unroll
        for (int i = 0; i < RM; i++) {
            #pragma unroll
            for (int r = 0; r < 4; r++) {
                float s1 = 0.f, s2 = 0.f;
                #pragma unroll
                for (int j = 0; j < RN; j++) {
                    float x = acc[i][j][r]; s1 += x; s2 += x * x;
                }
                #pragma unroll
                for (int m = 1; m < 16; m <<= 1) {
                    s1 += __shfl_xor(s1, m); s2 += __shfl_xor(s2, m);
                }
                if (l16 == 0) {
                    int row = wrow + i * 16 + quad * 4 + r;
                    part[row][(wave % WN) * 2]     = s1;
                    part[row][(wave % WN) * 2 + 1] = s2;
                }
            }
        }
        __syncthreads();
        float s3a[RM][4];
        #pragma unroll
        for (int i = 0; i < RM; i++) {
            #pragma unroll
            for (int r = 0; r < 4; r++) {
                int row = wrow + i * 16 + quad * 4 + r;
                float s1 = 0.f, s2 = 0.f;
                #pragma unroll
                for (int wn = 0; wn < WN; wn++) {
                    s1 += part[row][wn * 2]; s2 += part[row][wn * 2 + 1];
                }
                float mean = s1 * (1.f / N);
                float rstd = rsqrtf(s2 * (1.f / N) - mean * mean + LN_EPS);
                float s3 = 0.f;
                int grow = m0 + row;
                #pragma unroll
                for (int j = 0; j < RN; j++) {
                    int gcol = wcol + j * 16 + l16;
                    float y = (acc[i][j][r] - mean) * rstd * gam[j] + bet[j];
                    if constexpr (MODE == 1) {
                        float res = b2f(A[(size_t)grow * K + gcol]);  // residual
                        y = fmaxf(y, 0.f) + res;
                        Out[(size_t)grow * N + gcol] = f2b(y);
                    } else {
                        unsigned short ub = f2b(y);
                        Out[(size_t)grow * N + gcol] = ub;
                        float yr = b2f(ub);      // sq from ROUNDED z so the
                        s3 += yr * yr;           // gram diagonal cancels exactly
                    }
                }
                s3a[i][r] = s3;
            }
        }
        if constexpr (MODE == 2) {
            __syncthreads();
            #pragma unroll
            for (int i = 0; i < RM; i++)
                #pragma unroll
                for (int r = 0; r < 4; r++) {
                    float s3 = s3a[i][r];
                    #pragma unroll
                    for (int m = 1; m < 16; m <<= 1) s3 += __shfl_xor(s3, m);
                    if (l16 == 0) {
                        int row = wrow + i * 16 + quad * 4 + r;
                        part[row][wave % WN] = s3;
                    }
                }
            __syncthreads();
            if (l16 == 0 && (wave % WN) == 0) {
                #pragma unroll
                for (int i = 0; i < RM; i++)
                    #pragma unroll
                    for (int r = 0; r < 4; r++) {
                        int row = wrow + i * 16 + quad * 4 + r;
                        float t = 0.f;
                        #pragma unroll
                        for (int wn = 0; wn < WN; wn++) t += part[row][wn];
                        sqout[m0 + row] = t;
                    }
            }
        }
    }
}

// ---------------------------------------------------------------------------
// Per-batch Gram + distance + row-sum.  Gram = U.U^T so BOTH mfma operands
// read Z rows in the same [vec][k] layout (no transpose needed).
// grid: 64 batches x 8 row-tiles of 64; each wave owns 16 gram rows x all 512 cols.
__global__ __launch_bounds__(256) void gram_kernel(
    const unsigned short* __restrict__ Z, const float* __restrict__ sq,
    float* __restrict__ srow)
{
    constexpr int LDU = EMB + 8;   // 136 (272B stride, 16B aligned)
    __shared__ __align__(16) short Arows[64 * LDU];
    __shared__ __align__(16) short Brows[64 * LDU];

    const int batch = blockIdx.x >> 3, rt = blockIdx.x & 7;
    const int tid = threadIdx.x, wave = tid >> 6, lane = tid & 63;
    const int quad = lane >> 4, l16 = lane & 15;
    const int urow0 = batch * 512;
    const int ar0 = urow0 + rt * 64;

    #pragma unroll
    for (int it = 0; it < 4; ++it) {      // stage this WG's 64 A rows (64x128)
        int idx = tid + it * 256;
        int r = idx >> 4, c = (idx & 15) * 8;
        *(bfrag*)&Arows[r * LDU + c] =
            *(const bfrag*)(Z + (size_t)(ar0 + r) * EMB + c);
    }

    float rs[4] = {0.f, 0.f, 0.f, 0.f};
    float sqr[4];
    #pragma unroll
    for (int r = 0; r < 4; r++) sqr[r] = sq[ar0 + wave * 16 + quad * 4 + r];

    for (int ch = 0; ch < 8; ++ch) {      // stream 64-col chunks of U
        __syncthreads();
        #pragma unroll
        for (int it = 0; it < 4; ++it) {
            int idx = tid + it * 256;
            int r = idx >> 4, c = (idx & 15) * 8;
            *(bfrag*)&Brows[r * LDU + c] =
                *(const bfrag*)(Z + (size_t)(urow0 + ch * 64 + r) * EMB + c);
        }
        __syncthreads();
        ffrag acc[4];
        #pragma unroll
        for (int j = 0; j < 4; j++)
            #pragma unroll
            for (int r = 0; r < 4; r++) acc[j][r] = 0.f;
        #pragma unroll
        for (int kk = 0; kk < 4; ++kk) {
            bfrag a = *(const bfrag*)&Arows[(wave * 16 + l16) * LDU + kk * 32 + quad * 8];
            #pragma unroll
            for (int j = 0; j < 4; j++) {
                bfrag b = *(const bfrag*)&Brows[(j * 16 + l16) * LDU + kk * 32 + quad * 8];
                acc[j] = __builtin_amdgcn_mfma_f32_16x16x32_bf16(a, b, acc[j], 0, 0, 0);
            }
        }
        #pragma unroll
        for (int j = 0; j < 4; j++) {
            float sqc = sq[urow0 + ch * 64 + j * 16 + l16];
            #pragma unroll
            for (int r = 0; r < 4; r++) {
                float d2 = sqr[r] + sqc - 2.f * acc[j][r];
                rs[r] += sqrtf(fmaxf(d2, 1e-12f));
            }
        }
    }
    #pragma unroll
    for (int r = 0; r < 4; r++) {
        float v = rs[r];
        v += __shfl_xor(v, 1); v += __shfl_xor(v, 2);
        v += __shfl_xor(v, 4); v += __shfl_xor(v, 8);
        if (l16 == 0)
            srow[batch * 512 + rt * 64 + wave * 16 + quad * 4 + r] = v;
    }
}

// ---------------------------------------------------------------------------
// softmax over 512 classes, emit w (duplicated/halved) and f = sum w'_c u_c
__global__ __launch_bounds__(256) void softmax_f_kernel(
    const float* __restrict__ srow, const unsigned short* __restrict__ Z,
    float* __restrict__ fout, float* __restrict__ wout)
{
    const int b = blockIdx.x, tid = threadIdx.x;
    __shared__ float wsh[512];
    __shared__ float red[8];
    __shared__ float fred[128];
    constexpr float SC = (1.f / 512.f) * (1.f / TAU);

    float l0 = srow[b * 512 + tid] * SC;
    float l1 = srow[b * 512 + 256 + tid] * SC;
    float mx = fmaxf(l0, l1);
    #pragma unroll
    for (int m = 1; m < 64; m <<= 1) mx = fmaxf(mx, __shfl_xor(mx, m));
    if ((tid & 63) == 0) red[tid >> 6] = mx;
    __syncthreads();
    mx = fmaxf(fmaxf(red[0], red[1]), fmaxf(red[2], red[3]));
    float e0 = expf(l0 - mx), e1 = expf(l1 - mx);
    float sum = e0 + e1;
    #pragma unroll
    for (int m = 1; m < 64; m <<= 1) sum += __shfl_xor(sum, m);
    if ((tid & 63) == 0) red[4 + (tid >> 6)] = sum;
    __syncthreads();
    float inv = 1.f / (red[4] + red[5] + red[6] + red[7]);
    float w0 = e0 * inv, w1 = e1 * inv;
    wsh[tid] = w0; wsh[256 + tid] = w1;
    // each class appears twice in the 1024-row batch -> w = w'/2
    wout[b * 1024 + tid]       = w0 * 0.5f;
    wout[b * 1024 + 256 + tid] = w1 * 0.5f;
    wout[b * 1024 + 512 + tid] = w0 * 0.5f;
    wout[b * 1024 + 768 + tid] = w1 * 0.5f;
    __syncthreads();
    int e = tid & 127, half = tid >> 7;
    const unsigned short* zp = Z + (size_t)(b * 512 + half * 256) * EMB + e;
    float acc = 0.f;
    for (int c = 0; c < 256; c++)
        acc += wsh[half * 256 + c] * b2f(zp[(size_t)c * EMB]);
    if (half) fred[e] = acc;
    __syncthreads();
    if (!half) fout[b * EMB + e] = acc + fred[e];
}

// ---------------------------------------------------------------------------
extern "C" void kernel_launch(void* const* d_in, const int* in_sizes, int n_in,
                              void* d_out, int out_size, void* d_ws, size_t ws_size,
                              hipStream_t stream)
{
    (void)in_sizes; (void)n_in; (void)out_size; (void)ws_size;
    const float* H     = (const float*)d_in[0];
    // d_in[1] = batch_ptr (structure known: b = row >> 10), unused
    const int*   pairs = (const int*)d_in[2];
    const float* W_in  = (const float*)d_in[3];
    const float* b_in  = (const float*)d_in[4];
    const float* Wb    = (const float*)d_in[5];
    const float* bb    = (const float*)d_in[6];
    const float* lng   = (const float*)d_in[7];
    const float* lnb   = (const float*)d_in[8];
    const float* W_out = (const float*)d_in[9];
    const float* b_out = (const float*)d_in[10];
    const float* lnf_g = (const float*)d_in[11];
    const float* lnf_b = (const float*)d_in[12];

    float* f_out = (float*)d_out;                       // 64 x 128
    float* w_out = (float*)d_out + BATCH * EMB;         // 64 x 1024

    char* ws = (char*)d_ws;
    size_t off = 0;
    auto carve = [&](size_t bytes) -> void* {
        void* p = ws + off;
        off += (bytes + 255) & ~(size_t)255;
        return p;
    };
    unsigned short* X     = (unsigned short*)carve((size_t)NPAIR * IN_DIM * 2);
    unsigned short* WinT  = (unsigned short*)carve((size_t)HID * IN_DIM * 2);
    unsigned short* WbT   = (unsigned short*)carve((size_t)3 * HID * HID * 2);
    unsigned short* WoutT = (unsigned short*)carve((size_t)EMB * HID * 2);
    unsigned short* hA    = (unsigned short*)carve((size_t)NPAIR * HID * 2);
    unsigned short* hB    = (unsigned short*)carve((size_t)NPAIR * HID * 2);
    unsigned short* Zb    = (unsigned short*)carve((size_t)NPAIR * EMB * 2);
    float*          sq    = (float*)carve((size_t)NPAIR * 4);
    float*          srow  = (float*)carve((size_t)BATCH * 512 * 4);

    prep_w_kernel<<<768, 256, 0, stream>>>(W_in, Wb, W_out, WinT, WbT, WoutT);
    build_x_kernel<<<NPAIR * IN_DIM / 256, 256, 0, stream>>>(H, pairs, X);

    gemm_epi_kernel<IN_DIM, HID, 0><<<NPAIR / 64, 256, 0, stream>>>(
        X, WinT, b_in, nullptr, nullptr, hA, nullptr);
    gemm_epi_kernel<HID, HID, 1><<<NPAIR / 64, 256, 0, stream>>>(
        hA, WbT, bb, lng, lnb, hB, nullptr);
    gemm_epi_kernel<HID, HID, 1><<<NPAIR / 64, 256, 0, stream>>>(
        hB, WbT + 65536, bb + 256, lng + 256, lnb + 256, hA, nullptr);
    gemm_epi_kernel<HID, HID, 1><<<NPAIR / 64, 256, 0, stream>>>(
        hA, WbT + 131072, bb + 512, lng + 512, lnb + 512, hB, nullptr);
    gemm_epi_kernel<HID, EMB, 2><<<NPAIR / 64, 256, 0, stream>>>(
        hB, WoutT, b_out, lnf_g, lnf_b, Zb, sq);

    gram_kernel<<<BATCH * 8, 256, 0, stream>>>(Zb, sq, srow);
    softmax_f_kernel<<<BATCH, 256, 0, stream>>>(srow, Zb, f_out, w_out);
}

// Round 2
// 177.263 us; speedup vs baseline: 1.2088x; 1.2088x over previous
//
#include <hip/hip_runtime.h>
#include <hip/hip_bf16.h>

using bf16 = __hip_bfloat16;
typedef __attribute__((ext_vector_type(8))) short  bfrag;  // 8 bf16 (4 VGPRs)
typedef __attribute__((ext_vector_type(4))) float  ffrag;  // 4 f32 acc

#define DEVFN static __device__ __forceinline__

constexpr int BATCH  = 64;
constexpr int NPG    = 1024;
constexpr int IN_DIM = 64;
constexpr int HID    = 256;
constexpr int EMB    = 128;
constexpr int NPAIR  = BATCH * NPG / 2;   // 32768 unique rows
constexpr float TAU    = 0.25f;
constexpr float LN_EPS = 1e-5f;

constexpr int LDH = 264;  // h-buffer stride (shorts): 528 B, 16B-aligned rows
constexpr int LDB = 40;   // B-tile stride  (shorts):  80 B, 16B-aligned rows

DEVFN float b2f(unsigned short u) {
    union { unsigned int i; float f; } x; x.i = ((unsigned int)u) << 16; return x.f;
}
DEVFN unsigned short f2b(float f) {
    bf16 h = __float2bfloat16(f);
    unsigned short u; __builtin_memcpy(&u, &h, 2); return u;
}

// ---------------------------------------------------------------------------
// Transpose + cast weights to bf16 (N x K layout: both MFMA operands then load
// with the identical contiguous-k ds_read_b128 pattern).
__global__ __launch_bounds__(256) void prep_w_kernel(
    const float* __restrict__ Win, const float* __restrict__ Wb,
    const float* __restrict__ Wout,
    unsigned short* __restrict__ WinT, unsigned short* __restrict__ WbT,
    unsigned short* __restrict__ WoutT)
{
    int idx = blockIdx.x * 256 + threadIdx.x;          // 0 .. 196607 == 3*256*256
    {   // WbT[blk][n][k] = Wb[blk][k][n]
        int blk = idx >> 16, r = idx & 65535;
        int n = r >> 8, k = r & 255;
        WbT[idx] = f2b(Wb[blk * 65536 + k * 256 + n]);
    }
    if (idx < HID * IN_DIM) {                          // WinT[n][k] = Win[k][n]
        int n = idx >> 6, k = idx & 63;
        WinT[idx] = f2b(Win[k * HID + n]);
    }
    if (idx < EMB * HID) {                             // WoutT[n][k] = Wout[k][n]
        int n = idx >> 8, k = idx & 255;
        WoutT[idx] = f2b(Wout[k * EMB + n]);
    }
}

// ---------------------------------------------------------------------------
// One GEMM layer on the LDS-resident activation tile.
// Out(64xN) = h(64xK) @ Bt^T, epilogue per MODE:
//   MODE 0: +bias -> hbuf            MODE 1: h += relu(LN(.)g+b) -> hbuf
//   MODE 2: z = LN(.)g+b -> global Zb, plus sqout = ||z||^2
template<int K, int N, int MODE>
DEVFN void gemm_phase(short* hbuf, short* Bs, float (*part)[8],
                      const unsigned short* __restrict__ Bt,   // N x K
                      const float* __restrict__ bias,
                      const float* __restrict__ gamma,
                      const float* __restrict__ beta,
                      unsigned short* __restrict__ Zb,
                      float* __restrict__ sqout, int m0)
{
    constexpr int WN = N / 64;        // waves across N (4 for 256, 2 for 128)
    constexpr int WM = 4 / WN;
    constexpr int RM = (64 / WM) / 16;
    constexpr int RN = 4;

    const int tid  = threadIdx.x;
    const int wave = tid >> 6, lane = tid & 63;
    const int quad = lane >> 4, l16 = lane & 15;
    const int wrow = (wave / WN) * (64 / WM);
    const int wcol = (wave % WN) * 64;

    ffrag acc[RM][RN];
    #pragma unroll
    for (int i = 0; i < RM; i++)
        #pragma unroll
        for (int j = 0; j < RN; j++)
            #pragma unroll
            for (int r = 0; r < 4; r++) acc[i][j][r] = 0.f;

    for (int k0 = 0; k0 < K; k0 += 32) {
        __syncthreads();                      // also orders prior hbuf writes
        #pragma unroll
        for (int it = 0; it < N / 64; ++it) { // stage Bt tile Nx32
            int idx = tid + it * 256;
            int r = idx >> 2, c = (idx & 3) * 8;
            *(bfrag*)&Bs[r * LDB + c] =
                *(const bfrag*)(Bt + (size_t)r * K + k0 + c);
        }
        __syncthreads();
        bfrag af[RM], bfv[RN];
        #pragma unroll
        for (int i = 0; i < RM; i++)
            af[i] = *(const bfrag*)&hbuf[(wrow + i * 16 + l16) * LDH + k0 + quad * 8];
        #pragma unroll
        for (int j = 0; j < RN; j++)
            bfv[j] = *(const bfrag*)&Bs[(wcol + j * 16 + l16) * LDB + quad * 8];
        #pragma unroll
        for (int i = 0; i < RM; i++)
            #pragma unroll
            for (int j = 0; j < RN; j++)
                acc[i][j] = __builtin_amdgcn_mfma_f32_16x16x32_bf16(
                                af[i], bfv[j], acc[i][j], 0, 0, 0);
    }

    float bia[RN], gam[RN], bet[RN];
    #pragma unroll
    for (int j = 0; j < RN; j++) {
        int gcol = wcol + j * 16 + l16;
        bia[j] = bias[gcol];
        if constexpr (MODE != 0) { gam[j] = gamma[gcol]; bet[j] = beta[gcol]; }
    }
    #pragma unroll
    for (int i = 0; i < RM; i++)
        #pragma unroll
        for (int j = 0; j < RN; j++)
            #pragma unroll
            for (int r = 0; r < 4; r++) acc[i][j][r] += bia[j];

    if constexpr (MODE == 0) {
        __syncthreads();                      // all frag reads done before write
        #pragma unroll
        for (int i = 0; i < RM; i++)
            #pragma unroll
            for (int j = 0; j < RN; j++) {
                int gcol = wcol + j * 16 + l16;
                #pragma unroll
                for (int r = 0; r < 4; r++) {
                    int row = wrow + i * 16 + quad * 4 + r;
                    hbuf[row * LDH + gcol] = (short)f2b(acc[i][j][r]);
                }
            }
    } else {
        // per-row LN stats: lane partials over j, xor-shuffle over l16,
        // cross-wave via LDS
        #pragma unroll
        for (int i = 0; i < RM; i++) {
            #pragma unroll
            for (int r = 0; r < 4; r++) {
                float s1 = 0.f, s2 = 0.f;
                #pragma unroll
                for (int j = 0; j < RN; j++) {
                    float x = acc[i][j][r]; s1 += x; s2 += x * x;
                }
                #pragma unroll
                for (int m = 1; m < 16; m <<= 1) {
                    s1 += __shfl_xor(s1, m); s2 += __shfl_xor(s2, m);
                }
                if (l16 == 0) {
                    int row = wrow + i * 16 + quad * 4 + r;
                    part[row][(wave % WN) * 2]     = s1;
                    part[row][(wave % WN) * 2 + 1] = s2;
                }
            }
        }
        __syncthreads();   // also guarantees all MFMA frag reads of hbuf done
        float s3a[RM][4];
        #pragma unroll
        for (int i = 0; i < RM; i++) {
            #pragma unroll
            for (int r = 0; r < 4; r++) {
                int row = wrow + i * 16 + quad * 4 + r;
                float s1 = 0.f, s2 = 0.f;
                #pragma unroll
                for (int wn = 0; wn < WN; wn++) {
                    s1 += part[row][wn * 2]; s2 += part[row][wn * 2 + 1];
                }
                float mean = s1 * (1.f / N);
                float rstd = rsqrtf(s2 * (1.f / N) - mean * mean + LN_EPS);
                float s3 = 0.f;
                #pragma unroll
                for (int j = 0; j < RN; j++) {
                    int gcol = wcol + j * 16 + l16;
                    float y = (acc[i][j][r] - mean) * rstd * gam[j] + bet[j];
                    if constexpr (MODE == 1) {
                        float res = b2f((unsigned short)hbuf[row * LDH + gcol]);
                        y = fmaxf(y, 0.f) + res;
                        hbuf[row * LDH + gcol] = (short)f2b(y);
                    } else {
                        unsigned short ub = f2b(y);
                        Zb[(size_t)(m0 + row) * EMB + gcol] = ub;
                        float yr = b2f(ub);    // sq from ROUNDED z so the
                        s3 += yr * yr;         // gram diagonal cancels exactly
                    }
                }
                s3a[i][r] = s3;
            }
        }
        if constexpr (MODE == 2) {
            __syncthreads();
            #pragma unroll
            for (int i = 0; i < RM; i++)
                #pragma unroll
                for (int r = 0; r < 4; r++) {
                    float s3 = s3a[i][r];
                    #pragma unroll
                    for (int m = 1; m < 16; m <<= 1) s3 += __shfl_xor(s3, m);
                    if (l16 == 0) {
                        int row = wrow + i * 16 + quad * 4 + r;
                        part[row][wave % WN] = s3;
                    }
                }
            __syncthreads();
            if (l16 == 0 && (wave % WN) == 0) {
                #pragma unroll
                for (int i = 0; i < RM; i++)
                    #pragma unroll
                    for (int r = 0; r < 4; r++) {
                        int row = wrow + i * 16 + quad * 4 + r;
                        float t = 0.f;
                        #pragma unroll
                        for (int wn = 0; wn < WN; wn++) t += part[row][wn];
                        sqout[m0 + row] = t;
                    }
            }
        }
    }
}

// ---------------------------------------------------------------------------
// Fused: build X (|H[li]-H[ri]|) -> 5 GEMM layers, h resident in LDS.
__global__ __launch_bounds__(256) void fused_mlp_kernel(
    const float* __restrict__ H, const int* __restrict__ pairs,
    const unsigned short* __restrict__ WinT,
    const unsigned short* __restrict__ WbT,
    const unsigned short* __restrict__ WoutT,
    const float* __restrict__ b_in,  const float* __restrict__ bb,
    const float* __restrict__ lng,   const float* __restrict__ lnb,
    const float* __restrict__ b_out, const float* __restrict__ lnf_g,
    const float* __restrict__ lnf_b,
    unsigned short* __restrict__ Zb, float* __restrict__ sq)
{
    __shared__ __align__(16) short hbuf[64 * LDH];   // 33792 B
    __shared__ __align__(16) short Bs[256 * LDB];    // 20480 B
    __shared__ float part[64][8];                    //  2048 B

    const int tid = threadIdx.x;
    const int m0  = blockIdx.x * 64;

    // Phase 0: X tile (64x64 bf16) into hbuf cols [0,64)
    #pragma unroll
    for (int it = 0; it < 4; ++it) {
        int idx = tid + it * 256;            // 1024 float4-quads
        int r = idx >> 4, c4 = idx & 15;
        int p = m0 + r;
        int li = pairs[2 * p], ri = pairs[2 * p + 1];
        float4 a = *(const float4*)(H + (size_t)li * IN_DIM + c4 * 4);
        float4 b = *(const float4*)(H + (size_t)ri * IN_DIM + c4 * 4);
        short4 s;
        s.x = (short)f2b(fabsf(a.x - b.x));
        s.y = (short)f2b(fabsf(a.y - b.y));
        s.z = (short)f2b(fabsf(a.z - b.z));
        s.w = (short)f2b(fabsf(a.w - b.w));
        *(short4*)&hbuf[r * LDH + c4 * 4] = s;
    }
    // gemm_phase opens with __syncthreads() — X writes ordered there.

    gemm_phase<IN_DIM, HID, 0>(hbuf, Bs, part, WinT, b_in,
                               nullptr, nullptr, nullptr, nullptr, m0);
    gemm_phase<HID, HID, 1>(hbuf, Bs, part, WbT,
                            bb,       lng,       lnb,       nullptr, nullptr, m0);
    gemm_phase<HID, HID, 1>(hbuf, Bs, part, WbT + 65536,
                            bb + 256, lng + 256, lnb + 256, nullptr, nullptr, m0);
    gemm_phase<HID, HID, 1>(hbuf, Bs, part, WbT + 131072,
                            bb + 512, lng + 512, lnb + 512, nullptr, nullptr, m0);
    gemm_phase<HID, EMB, 2>(hbuf, Bs, part, WoutT, b_out,
                            lnf_g, lnf_b, Zb, sq, m0);
}

// ---------------------------------------------------------------------------
// Per-batch Gram + distance + row-sum.  Gram = U.U^T so BOTH mfma operands
// read Z rows in the same [vec][k] layout (no transpose needed).
__global__ __launch_bounds__(256) void gram_kernel(
    const unsigned short* __restrict__ Z, const float* __restrict__ sq,
    float* __restrict__ srow)
{
    constexpr int LDU = EMB + 8;   // 136 shorts (272 B, 16B-aligned)
    __shared__ __align__(16) short Arows[64 * LDU];
    __shared__ __align__(16) short Brows[64 * LDU];

    const int batch = blockIdx.x >> 3, rt = blockIdx.x & 7;
    const int tid = threadIdx.x, wave = tid >> 6, lane = tid & 63;
    const int quad = lane >> 4, l16 = lane & 15;
    const int urow0 = batch * 512;
    const int ar0 = urow0 + rt * 64;

    #pragma unroll
    for (int it = 0; it < 4; ++it) {      // stage this WG's 64 A rows (64x128)
        int idx = tid + it * 256;
        int r = idx >> 4, c = (idx & 15) * 8;
        *(bfrag*)&Arows[r * LDU + c] =
            *(const bfrag*)(Z + (size_t)(ar0 + r) * EMB + c);
    }

    float rs[4] = {0.f, 0.f, 0.f, 0.f};
    float sqr[4];
    #pragma unroll
    for (int r = 0; r < 4; r++) sqr[r] = sq[ar0 + wave * 16 + quad * 4 + r];

    for (int ch = 0; ch < 8; ++ch) {      // stream 64-row chunks of U
        __syncthreads();
        #pragma unroll
        for (int it = 0; it < 4; ++it) {
            int idx = tid + it * 256;
            int r = idx >> 4, c = (idx & 15) * 8;
            *(bfrag*)&Brows[r * LDU + c] =
                *(const bfrag*)(Z + (size_t)(urow0 + ch * 64 + r) * EMB + c);
        }
        __syncthreads();
        ffrag acc[4];
        #pragma unroll
        for (int j = 0; j < 4; j++)
            #pragma unroll
            for (int r = 0; r < 4; r++) acc[j][r] = 0.f;
        #pragma unroll
        for (int kk = 0; kk < 4; ++kk) {
            bfrag a = *(const bfrag*)&Arows[(wave * 16 + l16) * LDU + kk * 32 + quad * 8];
            #pragma unroll
            for (int j = 0; j < 4; j++) {
                bfrag b = *(const bfrag*)&Brows[(j * 16 + l16) * LDU + kk * 32 + quad * 8];
                acc[j] = __builtin_amdgcn_mfma_f32_16x16x32_bf16(a, b, acc[j], 0, 0, 0);
            }
        }
        #pragma unroll
        for (int j = 0; j < 4; j++) {
            float sqc = sq[urow0 + ch * 64 + j * 16 + l16];
            #pragma unroll
            for (int r = 0; r < 4; r++) {
                float d2 = sqr[r] + sqc - 2.f * acc[j][r];
                rs[r] += sqrtf(fmaxf(d2, 1e-12f));
            }
        }
    }
    #pragma unroll
    for (int r = 0; r < 4; r++) {
        float v = rs[r];
        v += __shfl_xor(v, 1); v += __shfl_xor(v, 2);
        v += __shfl_xor(v, 4); v += __shfl_xor(v, 8);
        if (l16 == 0)
            srow[batch * 512 + rt * 64 + wave * 16 + quad * 4 + r] = v;
    }
}

// ---------------------------------------------------------------------------
// softmax over 512 classes, emit w (duplicated/halved) and f = sum w'_c u_c
__global__ __launch_bounds__(256) void softmax_f_kernel(
    const float* __restrict__ srow, const unsigned short* __restrict__ Z,
    float* __restrict__ fout, float* __restrict__ wout)
{
    const int b = blockIdx.x, tid = threadIdx.x;
    __shared__ float wsh[512];
    __shared__ float red[8];
    __shared__ float fred[128];
    constexpr float SC = (1.f / 512.f) * (1.f / TAU);

    float l0 = srow[b * 512 + tid] * SC;
    float l1 = srow[b * 512 + 256 + tid] * SC;
    float mx = fmaxf(l0, l1);
    #pragma unroll
    for (int m = 1; m < 64; m <<= 1) mx = fmaxf(mx, __shfl_xor(mx, m));
    if ((tid & 63) == 0) red[tid >> 6] = mx;
    __syncthreads();
    mx = fmaxf(fmaxf(red[0], red[1]), fmaxf(red[2], red[3]));
    float e0 = expf(l0 - mx), e1 = expf(l1 - mx);
    float sum = e0 + e1;
    #pragma unroll
    for (int m = 1; m < 64; m <<= 1) sum += __shfl_xor(sum, m);
    if ((tid & 63) == 0) red[4 + (tid >> 6)] = sum;
    __syncthreads();
    float inv = 1.f / (red[4] + red[5] + red[6] + red[7]);
    float w0 = e0 * inv, w1 = e1 * inv;
    wsh[tid] = w0; wsh[256 + tid] = w1;
    // each class appears twice in the 1024-row batch -> w = w'/2
    wout[b * 1024 + tid]       = w0 * 0.5f;
    wout[b * 1024 + 256 + tid] = w1 * 0.5f;
    wout[b * 1024 + 512 + tid] = w0 * 0.5f;
    wout[b * 1024 + 768 + tid] = w1 * 0.5f;
    __syncthreads();
    int e = tid & 127, half = tid >> 7;
    const unsigned short* zp = Z + (size_t)(b * 512 + half * 256) * EMB + e;
    float acc = 0.f;
    for (int c = 0; c < 256; c++)
        acc += wsh[half * 256 + c] * b2f(zp[(size_t)c * EMB]);
    if (half) fred[e] = acc;
    __syncthreads();
    if (!half) fout[b * EMB + e] = acc + fred[e];
}

// ---------------------------------------------------------------------------
extern "C" void kernel_launch(void* const* d_in, const int* in_sizes, int n_in,
                              void* d_out, int out_size, void* d_ws, size_t ws_size,
                              hipStream_t stream)
{
    (void)in_sizes; (void)n_in; (void)out_size; (void)ws_size;
    const float* H     = (const float*)d_in[0];
    // d_in[1] = batch_ptr (structure known: b = row >> 10), unused
    const int*   pairs = (const int*)d_in[2];
    const float* W_in  = (const float*)d_in[3];
    const float* b_in  = (const float*)d_in[4];
    const float* Wb    = (const float*)d_in[5];
    const float* bb    = (const float*)d_in[6];
    const float* lng   = (const float*)d_in[7];
    const float* lnb   = (const float*)d_in[8];
    const float* W_out = (const float*)d_in[9];
    const float* b_out = (const float*)d_in[10];
    const float* lnf_g = (const float*)d_in[11];
    const float* lnf_b = (const float*)d_in[12];

    float* f_out = (float*)d_out;                       // 64 x 128
    float* w_out = (float*)d_out + BATCH * EMB;         // 64 x 1024

    char* ws = (char*)d_ws;
    size_t off = 0;
    auto carve = [&](size_t bytes) -> void* {
        void* p = ws + off;
        off += (bytes + 255) & ~(size_t)255;
        return p;
    };
    unsigned short* WinT  = (unsigned short*)carve((size_t)HID * IN_DIM * 2);
    unsigned short* WbT   = (unsigned short*)carve((size_t)3 * HID * HID * 2);
    unsigned short* WoutT = (unsigned short*)carve((size_t)EMB * HID * 2);
    unsigned short* Zb    = (unsigned short*)carve((size_t)NPAIR * EMB * 2);
    float*          sq    = (float*)carve((size_t)NPAIR * 4);
    float*          srow  = (float*)carve((size_t)BATCH * 512 * 4);

    prep_w_kernel<<<768, 256, 0, stream>>>(W_in, Wb, W_out, WinT, WbT, WoutT);

    fused_mlp_kernel<<<NPAIR / 64, 256, 0, stream>>>(
        H, pairs, WinT, WbT, WoutT,
        b_in, bb, lng, lnb, b_out, lnf_g, lnf_b, Zb, sq);

    gram_kernel<<<BATCH * 8, 256, 0, stream>>>(Zb, sq, srow);
    softmax_f_kernel<<<BATCH, 256, 0, stream>>>(srow, Zb, f_out, w_out);
}